// Round 1
// baseline (6920.959 us; speedup 1.0000x reference)
//
#include <hip/hip_runtime.h>
#include <math.h>

#define V      100000
#define H      256
#define TSTEPS 64
#define KTOP   10
#define NB1    512     // K1 grid
#define RPB    196     // rows per K1 block (512*196 = 100352 >= V)
#define RPW    49      // rows per wave (4 waves/block)
#define SENT_I 0x7ffff000
#define NEGBIG (-3.0e38f)

// ---------- small device helpers ----------
__device__ inline float sigm(float x) { return 1.0f / (1.0f + expf(-x)); }

__device__ inline void fence_arrive(unsigned* p) {
  __threadfence();
  __syncthreads();
  if (threadIdx.x == 0)
    __hip_atomic_fetch_add(p, 1u, __ATOMIC_RELEASE, __HIP_MEMORY_SCOPE_AGENT);
}
__device__ inline void spin_ge(unsigned* p, unsigned tgt) {
  if (threadIdx.x == 0) {
    while (__hip_atomic_load(p, __ATOMIC_ACQUIRE, __HIP_MEMORY_SCOPE_AGENT) < tgt)
      __builtin_amdgcn_s_sleep(8);
  }
  __syncthreads();
  __threadfence();
}

// dot(row[0:256], x) across one 64-lane wave; result in ALL lanes
__device__ inline float wave_rowdot(const float* __restrict__ row, float4 xv) {
  const int lane = threadIdx.x & 63;
  float4 wv = ((const float4*)row)[lane];
  float p = wv.x * xv.x + wv.y * xv.y + wv.z * xv.z + wv.w * xv.w;
#pragma unroll
  for (int off = 32; off > 0; off >>= 1) p += __shfl_xor(p, off);
  return p;
}

// ---------- init kernels ----------
__global__ void init_misc(float* __restrict__ hist, const float* __restrict__ mask,
                          unsigned* __restrict__ cnt) {
  int gid = blockIdx.x * blockDim.x + threadIdx.x;
  if (gid < 8) cnt[gid] = 0u;
  int stride = gridDim.x * blockDim.x;
  for (int i = gid; i < V; i += stride) hist[i] = mask[i];
}

// proc_mem[h] = tanh(dot(mem, mem_W[h,:]))   (one block per h)
__global__ __launch_bounds__(256) void pm_kernel(const float* __restrict__ mem,
                                                 const float* __restrict__ memW,
                                                 float* __restrict__ pm) {
  const int h = blockIdx.x, tid = threadIdx.x;
  const int w = tid >> 6, lane = tid & 63;
  __shared__ float red[4];
  const float4* m4 = (const float4*)mem;
  const float4* w4 = (const float4*)(memW + (size_t)h * V);
  float acc = 0.f;
  for (int i = tid; i < V / 4; i += 256) {
    float4 a = m4[i], b = w4[i];
    acc += a.x * b.x + a.y * b.y + a.z * b.z + a.w * b.w;
  }
#pragma unroll
  for (int off = 32; off > 0; off >>= 1) acc += __shfl_xor(acc, off);
  if (lane == 0) red[w] = acc;
  __syncthreads();
  if (tid == 0) pm[h] = tanhf(red[0] + red[1] + red[2] + red[3]);
}

// c1[h] = -(dot(pm, fg_mem_W[h,:]) + fg_mem_b[h])
__global__ __launch_bounds__(256) void c1_kernel(const float* __restrict__ pm,
                                                 const float* __restrict__ fgmW,
                                                 const float* __restrict__ fgmb,
                                                 float* __restrict__ c1) {
  __shared__ float pm_s[H];
  const int tid = threadIdx.x;
  pm_s[tid] = pm[tid];
  __syncthreads();
  const float4* p4 = (const float4*)pm_s;
  const float4* r4 = (const float4*)(fgmW + (size_t)tid * H);
  float acc = 0.f;
#pragma unroll 4
  for (int j = 0; j < H / 4; ++j) {
    float4 a = p4[j], b = r4[j];
    acc += a.x * b.x + a.y * b.y + a.z * b.z + a.w * b.w;
  }
  c1[tid] = -(acc + fgmb[tid]);
}

// ---------- K1: fc matvec + exp + per-block top10 + partial sums (+ prev probs write) ----------
__global__ __launch_bounds__(256) void k1(
    const float* __restrict__ fcW, const float* __restrict__ fcb,
    const float* __restrict__ hist, const float* __restrict__ cellR,
    float* __restrict__ e_buf, float* __restrict__ Spart,
    float* __restrict__ topkv, int* __restrict__ topki,
    float* __restrict__ probs_prev, const float* __restrict__ invS, int t) {
  const int b = blockIdx.x, tid = threadIdx.x;
  const int w = tid >> 6, lane = tid & 63;
  const int rowbase = b * RPB;
  __shared__ float cell_s[H];
  __shared__ float e_s[RPB], m_s[RPB], hist_s[RPB], fcb_s[RPB];
  __shared__ float wtv[4 * KTOP];
  __shared__ int wti[4 * KTOP];
  __shared__ float red[4];

  if (tid < H) cell_s[tid] = cellR[tid];
  for (int i = tid; i < RPB; i += 256) {
    int r = rowbase + i;
    hist_s[i] = (r < V) ? hist[r] : 0.f;
    fcb_s[i] = (r < V) ? fcb[r] : 0.f;
  }
  if (t > 0) {
    float inv = invS[0];
    for (int i = tid; i < RPB; i += 256) {
      int r = rowbase + i;
      if (r < V) probs_prev[r] = e_buf[r] * inv;
    }
  }
  __syncthreads();

  const float4 cv = ((const float4*)cell_s)[lane];
#pragma unroll 7
  for (int rr = 0; rr < RPW; ++rr) {
    const int local = w * RPW + rr;
    const int row = rowbase + local;
    float p = 0.f;
    if (row < V) {
      const float4 wv = ((const float4*)(fcW + (size_t)row * H))[lane];
      p = wv.x * cv.x + wv.y * cv.y + wv.z * cv.z + wv.w * cv.w;
    }
#pragma unroll
    for (int off = 32; off > 0; off >>= 1) p += __shfl_xor(p, off);
    if (lane == 0) {
      if (row < V) {
        float e = expf(p + fcb_s[local]);
        e_s[local] = e;
        m_s[local] = e * hist_s[local];
      } else {
        e_s[local] = 0.f;
        m_s[local] = -1.0f;
      }
    }
  }
  __syncthreads();

  // write e for this chunk (used for probs next step / K3)
  for (int i = tid; i < RPB; i += 256) {
    int r = rowbase + i;
    if (r < V) e_buf[r] = e_s[i];
  }
  // block partial sum of e
  float s = 0.f;
  for (int i = tid; i < RPB; i += 256) s += e_s[i];
#pragma unroll
  for (int off = 32; off > 0; off >>= 1) s += __shfl_xor(s, off);
  if (lane == 0) red[w] = s;
  __syncthreads();
  if (tid == 0) Spart[b] = red[0] + red[1] + red[2] + red[3];

  // per-wave exact top10 of m (value desc, index asc)
  const int myl = w * RPW + lane;
  float cv2 = (lane < RPW) ? m_s[myl] : -2.0f;
  int ci2 = (lane < RPW) ? (rowbase + myl) : (SENT_I + tid);
  for (int k = 0; k < KTOP; ++k) {
    float v = cv2;
    int i = ci2;
#pragma unroll
    for (int off = 32; off > 0; off >>= 1) {
      float vo = __shfl_xor(v, off);
      int io = __shfl_xor(i, off);
      if (vo > v || (vo == v && io < i)) { v = vo; i = io; }
    }
    if (lane == 0) { wtv[w * KTOP + k] = v; wti[w * KTOP + k] = i; }
    if (ci2 == i) cv2 = NEGBIG;
  }
  __syncthreads();
  // wave 0 merges the 4 wave-top10s -> block top10
  if (w == 0) {
    float v3 = (lane < 4 * KTOP) ? wtv[lane] : NEGBIG;
    int i3 = (lane < 4 * KTOP) ? wti[lane] : (SENT_I + 512 + lane);
    for (int k = 0; k < KTOP; ++k) {
      float v = v3;
      int i = i3;
#pragma unroll
      for (int off = 32; off > 0; off >>= 1) {
        float vo = __shfl_xor(v, off);
        int io = __shfl_xor(i, off);
        if (vo > v || (vo == v && io < i)) { v = vo; i = io; }
      }
      if (lane == 0) { topkv[b * KTOP + k] = v; topki[b * KTOP + k] = i; }
      if (i3 == i) v3 = NEGBIG;
    }
  }
}

// ---------- K2: merge+select (+outputs) then distributed GRU/gate chain ----------
__global__ __launch_bounds__(256) void k2(
    int t, const float* __restrict__ topkv, const int* __restrict__ topki,
    const float* __restrict__ Spart, const float* __restrict__ ui,
    float* __restrict__ hist, const float* __restrict__ emb,
    const float* __restrict__ Wih, const float* __restrict__ bih,
    const float* __restrict__ bhh, const float* __restrict__ fgcW,
    const float* __restrict__ c1, const float* __restrict__ pm,
    const float* __restrict__ valW, const float* __restrict__ valb,
    const float* __restrict__ cellR, float* __restrict__ cellW,
    float* __restrict__ x1, float* __restrict__ x2, float* __restrict__ invS,
    int* __restrict__ sel_slot, float* __restrict__ sign_slot,
    unsigned* __restrict__ cnt, float* __restrict__ out_sel,
    float* __restrict__ out_val, float* __restrict__ out_hit) {
  const int b = blockIdx.x, tid = threadIdx.x;
  const int w = tid >> 6, lane = tid & 63;
  const unsigned gen = (unsigned)(t + 2);
  __shared__ float g10v[KTOP];
  __shared__ int g10i[KTOP];
  __shared__ float xwv[4];
  __shared__ int xwi[4];

  if (b == 0) {
    if (t >= 0) {
      // thread-local top10 over 512*10 candidates
      float lv[KTOP];
      int li[KTOP];
#pragma unroll
      for (int k = 0; k < KTOP; ++k) { lv[k] = NEGBIG; li[k] = SENT_I + k; }
      for (int e = tid; e < NB1 * KTOP; e += 256) {
        float v = topkv[e];
        int idx = topki[e];
        if (v > lv[KTOP - 1] || (v == lv[KTOP - 1] && idx < li[KTOP - 1])) {
          lv[KTOP - 1] = v; li[KTOP - 1] = idx;
#pragma unroll
          for (int k = KTOP - 2; k >= 0; --k) {
            if (lv[k + 1] > lv[k] || (lv[k + 1] == lv[k] && li[k + 1] < li[k])) {
              float tv = lv[k]; lv[k] = lv[k + 1]; lv[k + 1] = tv;
              int ti = li[k]; li[k] = li[k + 1]; li[k + 1] = ti;
            }
          }
        }
      }
      // 10 block-wide extraction rounds -> global sorted top10
      for (int k = 0; k < KTOP; ++k) {
        float v = lv[0];
        int i = li[0];
#pragma unroll
        for (int off = 32; off > 0; off >>= 1) {
          float vo = __shfl_xor(v, off);
          int io = __shfl_xor(i, off);
          if (vo > v || (vo == v && io < i)) { v = vo; i = io; }
        }
        if (lane == 0) { xwv[w] = v; xwi[w] = i; }
        __syncthreads();
        float bv = xwv[0];
        int bi = xwi[0];
#pragma unroll
        for (int j = 1; j < 4; ++j) {
          if (xwv[j] > bv || (xwv[j] == bv && xwi[j] < bi)) { bv = xwv[j]; bi = xwi[j]; }
        }
        if (li[0] == bi && lv[0] == bv) {
#pragma unroll
          for (int kk = 0; kk < KTOP - 1; ++kk) { lv[kk] = lv[kk + 1]; li[kk] = li[kk + 1]; }
          lv[KTOP - 1] = NEGBIG; li[KTOP - 1] = SENT_I + 900 + k;
        }
        if (tid == 0) { g10v[k] = bv; g10i[k] = bi; }
        __syncthreads();
      }
      // hit / sel / outputs / hist update
      if (w == 0) {
        float u = (lane < KTOP) ? ui[g10i[lane]] : 0.f;
        unsigned long long ball = __ballot(lane < KTOP && u > 0.f);
        if (lane == 0) {
          int selv; float hitf;
          if (ball) { int k = __ffsll((unsigned long long)ball) - 1; selv = g10i[k]; hitf = 1.f; }
          else { selv = g10i[0]; hitf = 0.f; }
          out_sel[t] = (float)selv;
          out_hit[t] = hitf;
          if (hitf > 0.f) hist[selv] -= 1.0f;
          *sel_slot = selv;
          *sign_slot = (hitf > 0.f) ? 1.f : -1.f;
        }
      }
      __syncthreads();
      // S = sum of partials -> invS
      float s = 0.f;
      for (int e = tid; e < NB1; e += 256) s += Spart[e];
#pragma unroll
      for (int off = 32; off > 0; off >>= 1) s += __shfl_xor(s, off);
      if (lane == 0) xwv[w] = s;
      __syncthreads();
      if (tid == 0) invS[0] = 1.0f / (xwv[0] + xwv[1] + xwv[2] + xwv[3]);
    } else {
      if (tid == 0) { *sel_slot = 0; *sign_slot = 1.f; }
    }
    fence_arrive(&cnt[0]);
  } else if (b == 1) {
    if (t >= 0 && tid < 64) {  // value(t) = dot(cell(t), val_W) + val_b
      float4 cvv = ((const float4*)cellR)[lane];
      float4 vv = ((const float4*)valW)[lane];
      float p = cvv.x * vv.x + cvv.y * vv.y + cvv.z * vv.z + cvv.w * vv.w;
#pragma unroll
      for (int off = 32; off > 0; off >>= 1) p += __shfl_xor(p, off);
      if (lane == 0) out_val[t] = p + valb[0];
    }
  }
  spin_ge(&cnt[0], gen);
  if (t == TSTEPS - 1) return;  // no next-step cell needed

  const int sel = *(volatile int*)sel_slot;
  const float sign = *(volatile float*)sign_slot;
  const float4 e4 = ((const float4*)(emb + (size_t)sel * H))[lane];
  const float4 x0v = make_float4(sign * e4.x, sign * e4.y, sign * e4.z, sign * e4.w);

  // GRU layer 0 (h = 0 hidden): this block handles h in [b*8, b*8+8)
  {
    const float* W0 = Wih;
    const float* bi0 = bih;
    const float* bh0 = bhh;
#pragma unroll
    for (int s2 = 0; s2 < 2; ++s2) {
      const int h = b * 8 + w * 2 + s2;
      float g0 = wave_rowdot(W0 + (size_t)h * H, x0v);
      float g1 = wave_rowdot(W0 + (size_t)(H + h) * H, x0v);
      float g2 = wave_rowdot(W0 + (size_t)(2 * H + h) * H, x0v);
      if (lane == 0) {
        float r = sigm(g0 + bi0[h] + bh0[h]);
        float z = sigm(g1 + bi0[H + h] + bh0[H + h]);
        float n = tanhf(g2 + bi0[2 * H + h] + r * bh0[2 * H + h]);
        x1[h] = (1.f - z) * n;
      }
    }
  }
  fence_arrive(&cnt[1]);
  spin_ge(&cnt[1], 32u * gen);

  const float4 x1v = ((const float4*)x1)[lane];
  {
    const float* W1 = Wih + 3 * H * H;
    const float* bi1 = bih + 3 * H;
    const float* bh1 = bhh + 3 * H;
#pragma unroll
    for (int s2 = 0; s2 < 2; ++s2) {
      const int h = b * 8 + w * 2 + s2;
      float g0 = wave_rowdot(W1 + (size_t)h * H, x1v);
      float g1 = wave_rowdot(W1 + (size_t)(H + h) * H, x1v);
      float g2 = wave_rowdot(W1 + (size_t)(2 * H + h) * H, x1v);
      if (lane == 0) {
        float r = sigm(g0 + bi1[h] + bh1[h]);
        float z = sigm(g1 + bi1[H + h] + bh1[H + h]);
        float n = tanhf(g2 + bi1[2 * H + h] + r * bh1[2 * H + h]);
        x2[h] = (1.f - z) * n;
      }
    }
  }
  fence_arrive(&cnt[2]);
  spin_ge(&cnt[2], 32u * gen);

  const float4 x2v = ((const float4*)x2)[lane];
#pragma unroll
  for (int s2 = 0; s2 < 2; ++s2) {
    const int h = b * 8 + w * 2 + s2;
    float d = wave_rowdot(fgcW + (size_t)h * H, x2v);
    if (lane == 0) {
      float gt = sigm(c1[h] + d);
      cellW[h] = gt * pm[h] + (1.f - gt) * x2[h];
    }
  }
}

// ---------- K3: final probs write + final_hist ----------
__global__ __launch_bounds__(256) void k3(const float* __restrict__ e_buf,
                                          const float* __restrict__ invS,
                                          const float* __restrict__ hist,
                                          float* __restrict__ probs63,
                                          float* __restrict__ out_fh) {
  const int b = blockIdx.x, tid = threadIdx.x;
  const int rowbase = b * RPB;
  float inv = invS[0];
  for (int i = tid; i < RPB; i += 256) {
    int r = rowbase + i;
    if (r < V) {
      probs63[r] = e_buf[r] * inv;
      out_fh[r] = hist[r];
    }
  }
}

// ---------- host ----------
extern "C" void kernel_launch(void* const* d_in, const int* in_sizes, int n_in,
                              void* d_out, int out_size, void* d_ws, size_t ws_size,
                              hipStream_t stream) {
  const float* ui   = (const float*)d_in[0];
  const float* mask = (const float*)d_in[1];
  const float* mem  = (const float*)d_in[2];
  const float* emb  = (const float*)d_in[3];
  const float* Wih  = (const float*)d_in[4];
  const float* bih  = (const float*)d_in[6];
  const float* bhh  = (const float*)d_in[7];
  const float* fcW  = (const float*)d_in[8];
  const float* fcb  = (const float*)d_in[9];
  const float* valW = (const float*)d_in[10];
  const float* valb = (const float*)d_in[11];
  const float* memW = (const float*)d_in[12];
  const float* fgmW = (const float*)d_in[13];
  const float* fgmb = (const float*)d_in[14];
  const float* fgcW = (const float*)d_in[15];

  float* out = (float*)d_out;
  float* probs_out = out;                                  // 64*V
  float* out_sel = out + (size_t)TSTEPS * V;               // 64
  float* out_val = out_sel + TSTEPS;                       // 64
  float* out_hit = out_val + TSTEPS;                       // 64
  float* out_fh  = out_hit + TSTEPS;                       // V

  float* w = (float*)d_ws;
  float* hist  = w; w += V;
  float* e_buf = w; w += V;
  float* pm    = w; w += H;
  float* c1b   = w; w += H;
  float* x1    = w; w += H;
  float* x2    = w; w += H;
  float* cell  = w; w += 2 * H;
  float* Spart = w; w += NB1;
  float* topkv = w; w += NB1 * KTOP;
  int*   topki = (int*)w; w += NB1 * KTOP;
  float* invS  = w; w += 4;
  int*   sel_slot  = (int*)w; w += 4;
  float* sign_slot = w; w += 4;
  unsigned* cnt = (unsigned*)w; w += 8;

  init_misc<<<128, 256, 0, stream>>>(hist, mask, cnt);
  pm_kernel<<<H, 256, 0, stream>>>(mem, memW, pm);
  c1_kernel<<<1, 256, 0, stream>>>(pm, fgmW, fgmb, c1b);

  for (int t = -1; t < TSTEPS; ++t) {
    if (t >= 0) {
      float* pprev = (t > 0) ? (probs_out + (size_t)(t - 1) * V) : probs_out;
      k1<<<NB1, 256, 0, stream>>>(fcW, fcb, hist, cell + (t & 1) * H, e_buf, Spart,
                                  topkv, topki, pprev, invS, t);
    }
    const float* cR = cell + ((t >= 0) ? (t & 1) : 0) * H;
    float* cW = cell + (((t + 1) & 1)) * H;
    k2<<<32, 256, 0, stream>>>(t, topkv, topki, Spart, ui, hist, emb, Wih, bih, bhh,
                               fgcW, c1b, pm, valW, valb, cR, cW, x1, x2, invS,
                               sel_slot, sign_slot, cnt, out_sel, out_val, out_hit);
  }
  k3<<<NB1, 256, 0, stream>>>(e_buf, invS, hist, probs_out + (size_t)(TSTEPS - 1) * V, out_fh);
}